// Round 1
// baseline (450.861 us; speedup 1.0000x reference)
//
#include <hip/hip_runtime.h>
#include <stdint.h>

// Problem constants (fixed by reference setup_inputs)
#define BB 32
#define NN 131072            // 2^17 points per batch
#define BN (BB * NN)         // 4,194,304 = 2^22
#define TT 32768             // NUM_POINTS_TARGET
#define CELL 0.05f
#define TBITS 18
#define TSIZE (1 << TBITS)   // 262,144 slots per batch table (1 MB at 4B/slot)
#define TMASK (TSIZE - 1)
#define EMPTY32 0xFFFFFFFFu
#define LI17 0x1FFFFu        // low 17 bits = local point index

// Output layout in d_out (floats), in return order:
// y_sel [32,32768,3], idx_out [32,32768,2], mask_sel [32,32768],
// ul_idx [BN], ul_idx_inv [BN]
#define Y_OFF   0
#define IDX_OFF (BB * TT * 3)                    // 3,145,728
#define MSK_OFF (IDX_OFF + BB * TT * 2)          // 5,242,880
#define ULI_OFF (MSK_OFF + BB * TT)              // 6,291,456
#define ULV_OFF (ULI_OFF + BN)                   // 10,485,760

#define SCAN_TPB 256
#define SCAN_EPT 16
#define SCAN_EPB (SCAN_TPB * SCAN_EPT)           // 4096
#define SCAN_NBLK (BN / SCAN_EPB)                // 1024 (32 per batch)

typedef float v4f __attribute__((ext_vector_type(4)));
typedef unsigned int v4u __attribute__((ext_vector_type(4)));

// Quantize x -> 30-bit packed voxel key. 4 points/thread, float4 loads.
// y is reconstructible exactly: CELL*(float)g == CELL*rintf(x/CELL).
__global__ void k_keygen(const float* __restrict__ x, unsigned int* __restrict__ keys) {
    int t = blockIdx.x * blockDim.x + threadIdx.x;   // handles points 4t..4t+3
    const v4f* xv = (const v4f*)(x + 12 * t);        // 48B per thread, 16B aligned
    v4f va = __builtin_nontemporal_load(xv + 0);
    v4f vb = __builtin_nontemporal_load(xv + 1);
    v4f vc = __builtin_nontemporal_load(xv + 2);
    float p[12];
    p[0] = va[0]; p[1] = va[1]; p[2]  = va[2]; p[3]  = va[3];
    p[4] = vb[0]; p[5] = vb[1]; p[6]  = vb[2]; p[7]  = vb[3];
    p[8] = vc[0]; p[9] = vc[1]; p[10] = vc[2]; p[11] = vc[3];
    v4u kv;
    #pragma unroll
    for (int q = 0; q < 4; q++) {
        int g0 = (int)rintf(p[3 * q + 0] / CELL) + 512;
        int g1 = (int)rintf(p[3 * q + 1] / CELL) + 512;
        int g2 = (int)rintf(p[3 * q + 2] / CELL) + 512;
        g0 = min(max(g0, 0), 1023); g1 = min(max(g1, 0), 1023); g2 = min(max(g2, 0), 1023);
        kv[q] = ((unsigned int)g0 << 20) | ((unsigned int)g1 << 10) | (unsigned int)g2;
    }
    __builtin_nontemporal_store(kv, (v4u*)keys + t);
}

// Block -> (batch, chunk) mapping with XCD affinity (b%8 == blk%8, HW round-
// robin) AND temporal grouping: batches run in 4 sequential groups of 8, so
// each XCD's live table working set is ~1 MB (one batch) instead of 4 MB
// (all four of its batches) -> table stays L2-resident next to the streams.
// GBITS = log2(blocks per group) for the given blocks-per-batch count.
__device__ __forceinline__ void map_bc(int blk, int gbits, int& b, int& chunk) {
    int g = blk >> gbits;            // batch group (0..3)
    int r = blk & ((1 << gbits) - 1);
    b = (g << 3) | (r & 7);          // batch; b%8 == blk%8 -> XCD affinity kept
    chunk = r >> 3;
}

// Per-batch hash insert, 4-byte entries (tag6|li17). Load-first probe; tag
// filter avoids keys[] verify except for true dups + 1/64 false matches.
// Entries are monotonically decreasing => stale reads are safe.
__global__ void k_insert(const unsigned int* __restrict__ keys,
                         unsigned int* __restrict__ tab_all,
                         int* __restrict__ slotArr) {
    int b, chunk;
    map_bc(blockIdx.x, 12, b, chunk);            // 16384 blocks: 4096/group, 512/batch
    int li = (chunk << 8) + threadIdx.x;         // local idx in batch, < 2^17
    int i = (b << 17) + li;                      // flat idx
    unsigned int key = __builtin_nontemporal_load(&keys[i]);  // stream: don't evict tab
    unsigned int* tab = tab_all + ((size_t)b << TBITS);
    const unsigned int* bkeys = keys + (b << 17);
    unsigned int s = (key * 2654435761u) >> (32 - TBITS);
    unsigned int tag = (key * 0x85EBCA6Bu) >> 26;        // independent 6-bit tag
    unsigned int mine = (tag << 17) | (unsigned int)li;  // < 2^23 < EMPTY32
    for (;;) {
        unsigned int cur = tab[s];                       // plain load (L2-hit path)
        if (cur == EMPTY32) {
            unsigned int old = atomicCAS(&tab[s], EMPTY32, mine);
            if (old == EMPTY32) break;                   // claimed fresh slot
            cur = old;                                   // lost race: fall through
        }
        if ((cur >> 17) == tag && bkeys[cur & LI17] == key) {  // same voxel
            if (mine < cur) atomicMin(&tab[s], mine);    // rare (converges fast)
            break;
        }
        s = (s + 1) & TMASK;                             // different key: probe on
    }
    __builtin_nontemporal_store((int)s, &slotArr[i]);
}

// Scan pass A: resolve first-occurrence position per point from the (L2-warm)
// 4B table; flag bitmask; block partial sums. Same grouped XCD-affine mapping
// keeps each XCD's random tab reads inside one ~1 MB batch table at a time.
__global__ void k_scanA(const int* __restrict__ slotArr,
                        const unsigned int* __restrict__ tab_all,
                        int* __restrict__ pfirst, unsigned short* __restrict__ fmask,
                        int* __restrict__ bsums) {
    int b, chunk;
    map_bc(blockIdx.x, 8, b, chunk);             // 1024 blocks: 256/group, 32/batch
    int fbid = (b << 5) + chunk;                 // flat-order block id for bsums/fmask
    int t = threadIdx.x;
    int base = (b << 17) + chunk * SCAN_EPB + t * SCAN_EPT;  // flat
    const unsigned int* tab = tab_all + ((size_t)b << TBITS);
    int bbase = b << 17;
    int s = 0;
    unsigned int bits = 0;
    for (int e = 0; e < SCAN_EPT; e++) {
        int i = base + e;
        int sl = __builtin_nontemporal_load(&slotArr[i]);
        int p = (int)(tab[sl] & LI17) + bbase;
        __builtin_nontemporal_store(p, &pfirst[i]);
        int f = (p == i);
        bits |= (unsigned int)f << e;
        s += f;
    }
    fmask[fbid * SCAN_TPB + t] = (unsigned short)bits;
    __shared__ int sh[SCAN_TPB];
    sh[t] = s;
    __syncthreads();
    for (int off = SCAN_TPB / 2; off > 0; off >>= 1) {
        if (t < off) sh[t] += sh[t + off];
        __syncthreads();
    }
    if (t == 0) bsums[fbid] = sh[0];
}

// Scan pass B: exclusive scan of 1024 block sums; store grand total
__global__ void k_scanB(int* __restrict__ bsums, int* __restrict__ scal, int nb) {
    __shared__ int sh[1024];
    int t = threadIdx.x;
    int v = (t < nb) ? bsums[t] : 0;
    sh[t] = v;
    __syncthreads();
    for (int off = 1; off < 1024; off <<= 1) {
        int add = (t >= off) ? sh[t - off] : 0;
        __syncthreads();
        sh[t] += add;
        __syncthreads();
    }
    if (t < nb) bsums[t] = sh[t] - v;       // exclusive
    if (t == nb - 1) scal[2] = sh[t];       // total uniques U
}

// Scan pass C: write exclusive scan per element; scatter ul_idx_inv[rank] = pos
__global__ void k_scanC(const unsigned short* __restrict__ fmask,
                        const int* __restrict__ bsums,
                        int* __restrict__ scanArr, float* __restrict__ ulinv) {
    int t = threadIdx.x;
    int base = blockIdx.x * SCAN_EPB + t * SCAN_EPT;
    unsigned int bits = fmask[blockIdx.x * SCAN_TPB + t];
    int s = __popc(bits);
    __shared__ int sh[SCAN_TPB];
    sh[t] = s;
    __syncthreads();
    int v = s;
    for (int off = 1; off < SCAN_TPB; off <<= 1) {
        int add = (t >= off) ? sh[t - off] : 0;
        __syncthreads();
        sh[t] += add;
        __syncthreads();
    }
    int prefix = bsums[blockIdx.x] + sh[t] - v;  // exclusive prefix for this thread
    for (int e = 0; e < SCAN_EPT; e++) {
        int i = base + e;
        int f = (bits >> e) & 1;
        scanArr[i] = prefix;
        if (f) ulinv[prefix] = (float)i;
        prefix += f;
    }
}

// Fused: ul_idx gather + ul_idx_inv tail pad + stable top-k partition + output
// gather. y reconstructed exactly from the packed key (no x read). Grouped
// mapping keeps the scanArr[pfirst[i]] gather inside one 512 KB batch window
// per XCD at a time.
__global__ void k_select(const unsigned int* __restrict__ keys,
                         const int* __restrict__ pfirst,
                         const int* __restrict__ scanArr,
                         const unsigned short* __restrict__ fmask,
                         const int* __restrict__ scal,
                         float* __restrict__ ysel, float* __restrict__ idxout,
                         float* __restrict__ msel, float* __restrict__ uli,
                         float* __restrict__ ulinv) {
    int b, chunk;
    map_bc(blockIdx.x, 12, b, chunk);        // 16384 blocks: 4096/group, 512/batch
    int j = (chunk << 8) + threadIdx.x;      // local idx in batch
    int i = (b << 17) + j;                   // flat
    int pf = __builtin_nontemporal_load(&pfirst[i]);
    __builtin_nontemporal_store((float)scanArr[pf], &uli[i]);  // appearance rank
    int U = scal[2];
    if (i >= U) ulinv[i] = (float)BN;        // sentinel tail
    int base = scanArr[b << 17];
    int ones_before = scanArr[i] - base;
    int cnt1 = ((b == BB - 1) ? U : scanArr[(b + 1) << 17]) - base;
    int flag = (fmask[i >> 4] >> (i & 15)) & 1;
    int pos = flag ? ones_before : cnt1 + (j - ones_before);
    if (pos < TT) {
        unsigned int key = keys[i];
        float y0 = CELL * (float)((int)(key >> 20) - 512);
        float y1 = CELL * (float)((int)((key >> 10) & 1023) - 512);
        float y2 = CELL * (float)((int)(key & 1023) - 512);
        int yo = (b * TT + pos) * 3;
        ysel[yo + 0] = y0;
        ysel[yo + 1] = y1;
        ysel[yo + 2] = y2;
        int io = (b * TT + pos) * 2;
        idxout[io + 0] = (float)b;
        idxout[io + 1] = (float)j;
        msel[b * TT + pos] = flag ? 1.0f : 0.0f;
    }
}

extern "C" void kernel_launch(void* const* d_in, const int* in_sizes, int n_in,
                              void* d_out, int out_size, void* d_ws, size_t ws_size,
                              hipStream_t stream) {
    const float* x = (const float*)d_in[0];
    float* out = (float*)d_out;
    char* ws = (char*)d_ws;

    // ws layout (bytes): scalars 256 | slotArr BN*4 | pfirst BN*4 | scanArr BN*4
    //                    | bsums 4096 | fmask BN/16*2 | keys BN*4 | tab 32*TSIZE*4
    //                    => ~97 MB
    int* scal    = (int*)ws;
    int* slotArr = (int*)(ws + 256);
    int* pfirst  = slotArr + BN;
    int* scanArr = pfirst + BN;
    int* bsums   = scanArr + BN;
    unsigned short* fmask = (unsigned short*)(bsums + 1024);
    unsigned int* keys = (unsigned int*)((char*)fmask + (BN / 16) * 2);
    unsigned int* tab  = keys + BN;

    hipMemsetAsync(tab, 0xFF, (size_t)BB * TSIZE * 4, stream);  // all EMPTY32
    k_keygen<<<BN / 4 / 256, 256, 0, stream>>>(x, keys);
    k_insert<<<BN / 256, 256, 0, stream>>>(keys, tab, slotArr);
    k_scanA<<<SCAN_NBLK, SCAN_TPB, 0, stream>>>(slotArr, tab, pfirst, fmask, bsums);
    k_scanB<<<1, 1024, 0, stream>>>(bsums, scal, SCAN_NBLK);
    k_scanC<<<SCAN_NBLK, SCAN_TPB, 0, stream>>>(fmask, bsums, scanArr, out + ULV_OFF);
    k_select<<<BN / 256, 256, 0, stream>>>(keys, pfirst, scanArr, fmask, scal,
                                           out + Y_OFF, out + IDX_OFF, out + MSK_OFF,
                                           out + ULI_OFF, out + ULV_OFF);
}

// Round 2
// 380.872 us; speedup vs baseline: 1.1838x; 1.1838x over previous
//
#include <hip/hip_runtime.h>
#include <stdint.h>

// Problem constants (fixed by reference setup_inputs)
#define BB 32
#define NN 131072            // 2^17 points per batch
#define BN (BB * NN)         // 4,194,304 = 2^22
#define TT 32768             // NUM_POINTS_TARGET
#define CELL 0.05f
#define TBITS 18
#define TSIZE (1 << TBITS)   // 262,144 slots per batch table (1 MB at 4B/slot)
#define TMASK (TSIZE - 1)
#define EMPTY32 0xFFFFFFFFu
#define LI17 0x1FFFFu        // low 17 bits = local point index

// Output layout in d_out (floats), in return order:
// y_sel [32,32768,3], idx_out [32,32768,2], mask_sel [32,32768],
// ul_idx [BN], ul_idx_inv [BN]
#define Y_OFF   0
#define IDX_OFF (BB * TT * 3)                    // 3,145,728
#define MSK_OFF (IDX_OFF + BB * TT * 2)          // 5,242,880
#define ULI_OFF (MSK_OFF + BB * TT)              // 6,291,456
#define ULV_OFF (ULI_OFF + BN)                   // 10,485,760

#define SCAN_TPB 256
#define SCAN_EPT 16
#define SCAN_EPB (SCAN_TPB * SCAN_EPT)           // 4096
#define SCAN_NBLK (BN / SCAN_EPB)                // 1024 (32 per batch)

typedef float v4f __attribute__((ext_vector_type(4)));
typedef int   v4i __attribute__((ext_vector_type(4)));
typedef unsigned int v4u __attribute__((ext_vector_type(4)));

// Quantize x -> 30-bit packed voxel key. 4 points/thread, float4 loads.
// y is reconstructible exactly: CELL*(float)g == CELL*rintf(x/CELL).
__global__ void k_keygen(const float* __restrict__ x, unsigned int* __restrict__ keys) {
    int t = blockIdx.x * blockDim.x + threadIdx.x;   // handles points 4t..4t+3
    const v4f* xv = (const v4f*)(x + 12 * t);        // 48B per thread, 16B aligned
    v4f va = __builtin_nontemporal_load(xv + 0);
    v4f vb = __builtin_nontemporal_load(xv + 1);
    v4f vc = __builtin_nontemporal_load(xv + 2);
    float p[12];
    p[0] = va[0]; p[1] = va[1]; p[2]  = va[2]; p[3]  = va[3];
    p[4] = vb[0]; p[5] = vb[1]; p[6]  = vb[2]; p[7]  = vb[3];
    p[8] = vc[0]; p[9] = vc[1]; p[10] = vc[2]; p[11] = vc[3];
    v4u kv;
    #pragma unroll
    for (int q = 0; q < 4; q++) {
        int g0 = (int)rintf(p[3 * q + 0] / CELL) + 512;
        int g1 = (int)rintf(p[3 * q + 1] / CELL) + 512;
        int g2 = (int)rintf(p[3 * q + 2] / CELL) + 512;
        g0 = min(max(g0, 0), 1023); g1 = min(max(g1, 0), 1023); g2 = min(max(g2, 0), 1023);
        kv[q] = ((unsigned int)g0 << 20) | ((unsigned int)g1 << 10) | (unsigned int)g2;
    }
    __builtin_nontemporal_store(kv, (v4u*)keys + t);
}

// Per-batch hash insert, 4-byte entries (tag6|li17). batch = blockIdx % 32 =>
// XCD affinity; interleaved batches (NO temporal grouping — grouping measured
// -24% in round 1: narrower active address range hurt memory-side atomic
// throughput). Plain keys load: streamed lines stay in L2 and serve the
// bkeys[] dup-verify gathers. Entries monotonically decrease => stale reads ok.
__global__ void k_insert(const unsigned int* __restrict__ keys,
                         unsigned int* __restrict__ tab_all,
                         int* __restrict__ slotArr) {
    int blk = blockIdx.x;
    int b = blk & 31;
    int chunk = blk >> 5;
    int li = (chunk << 8) + threadIdx.x;   // local idx in batch, < 2^17
    int i = (b << 17) + li;                // flat idx
    unsigned int key = keys[i];
    unsigned int* tab = tab_all + ((size_t)b << TBITS);
    const unsigned int* bkeys = keys + (b << 17);
    unsigned int s = (key * 2654435761u) >> (32 - TBITS);
    unsigned int tag = (key * 0x85EBCA6Bu) >> 26;        // independent 6-bit tag
    unsigned int mine = (tag << 17) | (unsigned int)li;  // < 2^23 < EMPTY32
    for (;;) {
        unsigned int cur = tab[s];                       // plain load (L2-hit path)
        if (cur == EMPTY32) {
            unsigned int old = atomicCAS(&tab[s], EMPTY32, mine);
            if (old == EMPTY32) break;                   // claimed fresh slot
            cur = old;                                   // lost race: fall through
        }
        if ((cur >> 17) == tag && bkeys[cur & LI17] == key) {  // same voxel
            if (mine < cur) atomicMin(&tab[s], mine);    // rare (converges fast)
            break;
        }
        s = (s + 1) & TMASK;                             // different key: probe on
    }
    __builtin_nontemporal_store((int)s, &slotArr[i]);
}

// Scan pass A: resolve first-occurrence position per point from the (L2-warm)
// 4B table; flag bitmask; block partial sums. Same %32 XCD swizzle.
// Streams (slotArr read, pfirst write) vectorized to int4.
__global__ void k_scanA(const int* __restrict__ slotArr,
                        const unsigned int* __restrict__ tab_all,
                        int* __restrict__ pfirst, unsigned short* __restrict__ fmask,
                        int* __restrict__ bsums) {
    int blk = blockIdx.x;
    int b = blk & 31;
    int chunk = blk >> 5;                  // < 32
    int fbid = (b << 5) + chunk;           // flat-order block id for bsums/fmask
    int t = threadIdx.x;
    int base = (b << 17) + chunk * SCAN_EPB + t * SCAN_EPT;  // flat, mult of 16
    const unsigned int* tab = tab_all + ((size_t)b << TBITS);
    int bbase = b << 17;
    int s = 0;
    unsigned int bits = 0;
    const v4i* slv = (const v4i*)(slotArr + base);
    v4i* pfv = (v4i*)(pfirst + base);
    #pragma unroll
    for (int q = 0; q < 4; q++) {
        v4i sl = slv[q];
        v4i pv;
        #pragma unroll
        for (int e = 0; e < 4; e++) {
            int idx = 4 * q + e;
            int p = (int)(tab[sl[e]] & LI17) + bbase;
            pv[e] = p;
            int f = (p == base + idx);
            bits |= (unsigned int)f << idx;
            s += f;
        }
        pfv[q] = pv;
    }
    fmask[fbid * SCAN_TPB + t] = (unsigned short)bits;
    __shared__ int sh[SCAN_TPB];
    sh[t] = s;
    __syncthreads();
    for (int off = SCAN_TPB / 2; off > 0; off >>= 1) {
        if (t < off) sh[t] += sh[t + off];
        __syncthreads();
    }
    if (t == 0) bsums[fbid] = sh[0];
}

// Scan pass C with fused pass B: every block redundantly scans the 1024 RAW
// block sums (4 KB, L2-broadcast after first block) -> its own exclusive
// block prefix + grand total; removes the serializing 1-block scanB dispatch.
// Then per-element exclusive scan; scatter ul_idx_inv[rank] = pos; int4 stores.
__global__ void k_scanC(const unsigned short* __restrict__ fmask,
                        const int* __restrict__ bsums,
                        int* __restrict__ scanArr, float* __restrict__ ulinv,
                        int* __restrict__ scal) {
    int t = threadIdx.x;
    __shared__ int shc[SCAN_TPB];
    // --- fused scanB: inclusive scan of 256 chunk-sums (4 bsums per thread) ---
    int s0 = bsums[4 * t + 0], s1 = bsums[4 * t + 1];
    int s2 = bsums[4 * t + 2], s3 = bsums[4 * t + 3];
    int cs = s0 + s1 + s2 + s3;
    shc[t] = cs;
    __syncthreads();
    for (int off = 1; off < SCAN_TPB; off <<= 1) {
        int add = (t >= off) ? shc[t - off] : 0;
        __syncthreads();
        shc[t] += add;
        __syncthreads();
    }
    __shared__ int bp;
    int q = blockIdx.x >> 2, r = blockIdx.x & 3;
    if (t == q) {
        int ex = shc[t] - cs;              // exclusive prefix of chunk q
        if (r > 0) ex += s0;
        if (r > 1) ex += s1;
        if (r > 2) ex += s2;
        bp = ex;                           // sum of bsums[0 .. blockIdx.x)
    }
    if (blockIdx.x == 0 && t == SCAN_TPB - 1) scal[2] = shc[t];  // total U
    __syncthreads();
    int blockpref = bp;
    // --- per-element scan within this block ---
    unsigned int bits = fmask[blockIdx.x * SCAN_TPB + t];
    int s = __popc(bits);
    __syncthreads();                       // shc reuse
    shc[t] = s;
    __syncthreads();
    int v = s;
    for (int off = 1; off < SCAN_TPB; off <<= 1) {
        int add = (t >= off) ? shc[t - off] : 0;
        __syncthreads();
        shc[t] += add;
        __syncthreads();
    }
    int prefix = blockpref + shc[t] - v;   // exclusive prefix for this thread
    int base = blockIdx.x * SCAN_EPB + t * SCAN_EPT;   // mult of 16
    v4i* out = (v4i*)(scanArr + base);
    #pragma unroll
    for (int qq = 0; qq < 4; qq++) {
        v4i o;
        #pragma unroll
        for (int e = 0; e < 4; e++) {
            int idx = 4 * qq + e;
            int f = (bits >> idx) & 1;
            o[e] = prefix;
            if (f) ulinv[prefix] = (float)(base + idx);
            prefix += f;
        }
        out[qq] = o;
    }
}

// Fused: ul_idx gather + ul_idx_inv tail pad + stable top-k partition + output
// gather. y reconstructed exactly from the packed key (no x read). %32 swizzle
// keeps the scanArr[pfirst[i]] gather in the batch's 512 KB window.
// 4 points/thread: int4 stream loads (pfirst, scanArr, keys), vec uli store.
__global__ void k_select(const unsigned int* __restrict__ keys,
                         const int* __restrict__ pfirst,
                         const int* __restrict__ scanArr,
                         const unsigned short* __restrict__ fmask,
                         const int* __restrict__ scal,
                         float* __restrict__ ysel, float* __restrict__ idxout,
                         float* __restrict__ msel, float* __restrict__ uli,
                         float* __restrict__ ulinv) {
    int blk = blockIdx.x;                  // BN/1024 = 4096 blocks
    int b = blk & 31;
    int chunk = blk >> 5;                  // 0..127
    int j0 = (chunk << 10) + (threadIdx.x << 2);   // local idx of first point
    int i0 = (b << 17) + j0;               // flat, mult of 4 -> 16B aligned
    v4i pf = *(const v4i*)(pfirst + i0);
    v4i sa = *(const v4i*)(scanArr + i0);
    v4u kv = *(const v4u*)(keys + i0);
    int U = scal[2];
    int base = scanArr[b << 17];           // uniform per batch
    int cnt1 = ((b == BB - 1) ? U : scanArr[(b + 1) << 17]) - base;
    unsigned int fb = fmask[i0 >> 4];      // 4 consecutive i share one u16
    v4f ul;
    #pragma unroll
    for (int e = 0; e < 4; e++) ul[e] = (float)scanArr[pf[e]];
    __builtin_nontemporal_store(ul, (v4f*)(uli + i0));
    #pragma unroll
    for (int e = 0; e < 4; e++) {
        int i = i0 + e;
        int j = j0 + e;
        if (i >= U) ulinv[i] = (float)BN;  // sentinel tail
        int ones_before = sa[e] - base;
        int flag = (fb >> (i & 15)) & 1;
        int pos = flag ? ones_before : cnt1 + (j - ones_before);
        if (pos < TT) {
            unsigned int key = kv[e];
            float y0 = CELL * (float)((int)(key >> 20) - 512);
            float y1 = CELL * (float)((int)((key >> 10) & 1023) - 512);
            float y2 = CELL * (float)((int)(key & 1023) - 512);
            int yo = (b * TT + pos) * 3;
            ysel[yo + 0] = y0;
            ysel[yo + 1] = y1;
            ysel[yo + 2] = y2;
            int io = (b * TT + pos) * 2;
            idxout[io + 0] = (float)b;
            idxout[io + 1] = (float)j;
            msel[b * TT + pos] = flag ? 1.0f : 0.0f;
        }
    }
}

extern "C" void kernel_launch(void* const* d_in, const int* in_sizes, int n_in,
                              void* d_out, int out_size, void* d_ws, size_t ws_size,
                              hipStream_t stream) {
    const float* x = (const float*)d_in[0];
    float* out = (float*)d_out;
    char* ws = (char*)d_ws;

    // ws layout (bytes): scalars 256 | slotArr BN*4 | pfirst BN*4 | scanArr BN*4
    //                    | bsums 4096 | fmask BN/16*2 | keys BN*4 | tab 32*TSIZE*4
    //                    => ~97 MB
    int* scal    = (int*)ws;
    int* slotArr = (int*)(ws + 256);
    int* pfirst  = slotArr + BN;
    int* scanArr = pfirst + BN;
    int* bsums   = scanArr + BN;
    unsigned short* fmask = (unsigned short*)(bsums + 1024);
    unsigned int* keys = (unsigned int*)((char*)fmask + (BN / 16) * 2);
    unsigned int* tab  = keys + BN;

    hipMemsetAsync(tab, 0xFF, (size_t)BB * TSIZE * 4, stream);  // all EMPTY32
    k_keygen<<<BN / 4 / 256, 256, 0, stream>>>(x, keys);
    k_insert<<<BN / 256, 256, 0, stream>>>(keys, tab, slotArr);
    k_scanA<<<SCAN_NBLK, SCAN_TPB, 0, stream>>>(slotArr, tab, pfirst, fmask, bsums);
    k_scanC<<<SCAN_NBLK, SCAN_TPB, 0, stream>>>(fmask, bsums, scanArr, out + ULV_OFF,
                                                scal);
    k_select<<<BN / 1024, 256, 0, stream>>>(keys, pfirst, scanArr, fmask, scal,
                                            out + Y_OFF, out + IDX_OFF, out + MSK_OFF,
                                            out + ULI_OFF, out + ULV_OFF);
}